// Round 2
// baseline (648.766 us; speedup 1.0000x reference)
//
#include <hip/hip_runtime.h>

// GSA layer: q/k/v = x@W^T+b ; row-attn + col-attn with -gw*(i-j)^2 bias ; out = (r+c)@Wo^T+bo
// All GEMM/attention compute in fp16 MFMA (fp32 accum), softmax in fp32.
// fp16 (not bf16): 8x smaller mantissa eps at identical MFMA rate; the harness
// threshold (8*eps_bf16*max) needs the full-pipeline rounding cascade ~3x
// below bf16 level (round-1 measured 0.207 vs 0.081 with bf16).
//
// Workspace layout (~264 MiB):
//   [0)     x_f16  (64 MiB)  -- reused as attn buffer after QKV GEMMs
//   [+NE]   Wq,Wk,Wv,Wo f16 (4 x 2 MiB)
//   [+8MiB] q, k, v f16 (3 x 64 MiB)

typedef _Float16 f16;
typedef __attribute__((ext_vector_type(8))) _Float16 f16x8;
typedef __attribute__((ext_vector_type(4))) float f32x4;

#define DEV __device__ __forceinline__

// ---------------- convert f32 -> f16 (vectorized, grid-stride) --------------
__global__ __launch_bounds__(256) void k_cvt_f16(const float* __restrict__ in,
                                                 f16* __restrict__ out, int n8) {
  int stride = gridDim.x * blockDim.x;
  for (int i = blockIdx.x * blockDim.x + threadIdx.x; i < n8; i += stride) {
    const float4* p = (const float4*)in + (size_t)i * 2;
    float4 a = p[0];
    float4 b = p[1];
    f16x8 o;
    o[0] = (f16)a.x; o[1] = (f16)a.y; o[2] = (f16)a.z; o[3] = (f16)a.w;
    o[4] = (f16)b.x; o[5] = (f16)b.y; o[6] = (f16)b.z; o[7] = (f16)b.w;
    *(f16x8*)(out + (size_t)i * 8) = o;
  }
}

// ------- C[M,N] = A[M,K] * B[N,K]^T + bias[N]; f16 in, f16 or f32 out -------
// m97 structure: 128x128 tile, BK=64, global_load_lds width 16, 2x2 waves,
// 4x4 16x16 fragments per wave. M,N,K multiples of 128/128/64.
template<bool C_F32>
__global__ __launch_bounds__(256) void k_gemm_bt(const f16* __restrict__ A,
                                                 const f16* __restrict__ B,
                                                 const float* __restrict__ bias,
                                                 void* __restrict__ Cout,
                                                 int M, int N, int K) {
  __shared__ f16 As[128 * 64];
  __shared__ f16 Bs[128 * 64];
  const int tid = threadIdx.x;
  const int lane = tid & 63;
  const int wid = tid >> 6;
  const int bm = blockIdx.y, bn = blockIdx.x;
  const int wr = wid >> 1, wc = wid & 1;

  f32x4 acc[4][4];
#pragma unroll
  for (int i = 0; i < 4; ++i)
#pragma unroll
    for (int j = 0; j < 4; ++j) acc[i][j] = (f32x4){0.f, 0.f, 0.f, 0.f};

  const int srow = lane >> 3;        // row within an 8-row chunk
  const int scol = (lane & 7) * 8;   // col in elements
  const int KT = K >> 6;

  for (int kt = 0; kt < KT; ++kt) {
#pragma unroll
    for (int j = 0; j < 4; ++j) {
      const int c = wid * 4 + j;     // 16 chunks x 1KiB cover the 16KiB tile
      const int row = c * 8 + srow;
      const size_t ga = (size_t)(bm * 128 + row) * K + kt * 64 + scol;
      const size_t gb = (size_t)(bn * 128 + row) * K + kt * 64 + scol;
      __builtin_amdgcn_global_load_lds(
          (const __attribute__((address_space(1))) void*)(A + ga),
          (__attribute__((address_space(3))) void*)((char*)As + c * 1024), 16, 0, 0);
      __builtin_amdgcn_global_load_lds(
          (const __attribute__((address_space(1))) void*)(B + gb),
          (__attribute__((address_space(3))) void*)((char*)Bs + c * 1024), 16, 0, 0);
    }
    __syncthreads();
#pragma unroll
    for (int ks = 0; ks < 2; ++ks) {
      f16x8 af[4], bfr[4];
#pragma unroll
      for (int i = 0; i < 4; ++i) {
        af[i]  = *(const f16x8*)&As[(wr * 64 + i * 16 + (lane & 15)) * 64 + ks * 32 + (lane >> 4) * 8];
        bfr[i] = *(const f16x8*)&Bs[(wc * 64 + i * 16 + (lane & 15)) * 64 + ks * 32 + (lane >> 4) * 8];
      }
#pragma unroll
      for (int mi = 0; mi < 4; ++mi)
#pragma unroll
        for (int ni = 0; ni < 4; ++ni)
          acc[mi][ni] = __builtin_amdgcn_mfma_f32_16x16x32_f16(af[mi], bfr[ni], acc[mi][ni], 0, 0, 0);
    }
    __syncthreads();
  }

  // epilogue: C/D layout col = lane&15, row = (lane>>4)*4 + reg (m89/m91)
  const int mrow0 = bm * 128 + wr * 64 + (lane >> 4) * 4;
  const int ncol0 = bn * 128 + wc * 64 + (lane & 15);
#pragma unroll
  for (int ni = 0; ni < 4; ++ni) {
    const int col = ncol0 + ni * 16;
    const float bv = bias[col];
#pragma unroll
    for (int mi = 0; mi < 4; ++mi) {
#pragma unroll
      for (int r = 0; r < 4; ++r) {
        const int row = mrow0 + mi * 16 + r;
        const float val = acc[mi][ni][r] + bv;
        if (C_F32) ((float*)Cout)[(size_t)row * N + col] = val;
        else       ((f16*)Cout)[(size_t)row * N + col] = (f16)val;
      }
    }
  }
}

// ------------------- axis attention: one block per (b,line) -----------------
// SEQ = 64 positions, D = 1024, 4 waves. IS_COL=false: line=(b,h), stride D.
// IS_COL=true: line=(b,w), stride W*D, accumulates into attn (RMW; safe since
// each element is touched by exactly one thread and kernels run sequentially).
template<bool IS_COL>
__global__ __launch_bounds__(256) void k_attn(const f16* __restrict__ q,
                                              const f16* __restrict__ k,
                                              const f16* __restrict__ v,
                                              f16* __restrict__ attn,
                                              const float* __restrict__ sigma) {
  __shared__ union { float S[64][68]; f16 Vt[256][72]; } sm;  // S dead before Vt lives
  __shared__ f16 P[64][72];

  const int tid = threadIdx.x;
  const int lane = tid & 63;
  const int wid = tid >> 6;
  const int blk = blockIdx.x;

  size_t base; int sstr;
  if (IS_COL) { base = (size_t)(blk >> 6) * (64 * 64 * 1024) + (size_t)(blk & 63) * 1024; sstr = 64 * 1024; }
  else        { base = (size_t)blk * (64 * 1024); sstr = 1024; }

  const float sg = sigma[0];
  const float gw = 0.5f / (sg * sg);

  const int m0 = wid * 16;   // wave's query rows
  const int lr = lane & 15;
  const int lq = lane >> 4;

  // ---- phase A: S = Q K^T (each wave: 16 rows x all 64 keys) ----
  f32x4 sacc[4];
#pragma unroll
  for (int nt = 0; nt < 4; ++nt) sacc[nt] = (f32x4){0.f, 0.f, 0.f, 0.f};
  const f16* qp = q + base + (size_t)(m0 + lr) * sstr + lq * 8;
  const f16* kp = k + base + (size_t)lr * sstr + lq * 8;
#pragma unroll 2
  for (int ks = 0; ks < 32; ++ks) {
    f16x8 af = *(const f16x8*)(qp + ks * 32);
#pragma unroll
    for (int nt = 0; nt < 4; ++nt) {
      f16x8 bfr = *(const f16x8*)(kp + (size_t)nt * 16 * sstr + ks * 32);
      sacc[nt] = __builtin_amdgcn_mfma_f32_16x16x32_f16(af, bfr, sacc[nt], 0, 0, 0);
    }
  }
#pragma unroll
  for (int nt = 0; nt < 4; ++nt)
#pragma unroll
    for (int r = 0; r < 4; ++r) {
      const int row = m0 + lq * 4 + r;
      const int col = nt * 16 + lr;
      const float dd = (float)(row - col);
      sm.S[row][col] = sacc[nt][r] - gw * dd * dd;   // gaussian distance bias
    }
  __syncthreads();

  // ---- phase B: row softmax, 4 threads per row, shfl_xor reduce ----
  {
    const int r = tid >> 2, s4 = tid & 3;
    const float4* sp = (const float4*)&sm.S[r][s4 * 16];
    float vals[16];
#pragma unroll
    for (int j = 0; j < 4; ++j) {
      float4 t = sp[j];
      vals[j * 4 + 0] = t.x; vals[j * 4 + 1] = t.y; vals[j * 4 + 2] = t.z; vals[j * 4 + 3] = t.w;
    }
    float mx = vals[0];
#pragma unroll
    for (int j = 1; j < 16; ++j) mx = fmaxf(mx, vals[j]);
    mx = fmaxf(mx, __shfl_xor(mx, 1));
    mx = fmaxf(mx, __shfl_xor(mx, 2));
    float sum = 0.f;
#pragma unroll
    for (int j = 0; j < 16; ++j) { vals[j] = __expf(vals[j] - mx); sum += vals[j]; }
    sum += __shfl_xor(sum, 1);
    sum += __shfl_xor(sum, 2);
    const float inv = 1.f / sum;
#pragma unroll
    for (int j = 0; j < 16; ++j) P[r][s4 * 16 + j] = (f16)(vals[j] * inv);
  }
  __syncthreads();

  // ---- phase C: O = P V ; V transposed through LDS in 256-col chunks ----
  const f16x8 af0 = *(const f16x8*)&P[m0 + lr][lq * 8];        // P k-slice 0..31
  const f16x8 af1 = *(const f16x8*)&P[m0 + lr][32 + lq * 8];   // P k-slice 32..63

  const int kr = tid & 63;   // v row this thread transposes
  const int cg = tid >> 6;   // 64-col group
  const f16* vp = v + base + (size_t)kr * sstr;

  for (int c = 0; c < 4; ++c) {
#pragma unroll
    for (int j8 = 0; j8 < 8; ++j8) {
      const int cl = cg * 64 + j8 * 8;
      f16x8 vv = *(const f16x8*)(vp + c * 256 + cl);
#pragma unroll
      for (int e = 0; e < 8; ++e) sm.Vt[cl + e][kr] = vv[e];
    }
    __syncthreads();
#pragma unroll
    for (int nt = 0; nt < 16; ++nt) {
      const f16x8 bf0 = *(const f16x8*)&sm.Vt[nt * 16 + lr][lq * 8];
      const f16x8 bf1 = *(const f16x8*)&sm.Vt[nt * 16 + lr][32 + lq * 8];
      f32x4 o = (f32x4){0.f, 0.f, 0.f, 0.f};
      o = __builtin_amdgcn_mfma_f32_16x16x32_f16(af0, bf0, o, 0, 0, 0);
      o = __builtin_amdgcn_mfma_f32_16x16x32_f16(af1, bf1, o, 0, 0, 0);
#pragma unroll
      for (int r = 0; r < 4; ++r) {
        const int row = m0 + lq * 4 + r;
        const int col = c * 256 + nt * 16 + lr;
        const size_t addr = base + (size_t)row * sstr + col;
        float val = o[r];
        if (IS_COL) val += (float)attn[addr];
        attn[addr] = (f16)val;
      }
    }
    __syncthreads();
  }
}

extern "C" void kernel_launch(void* const* d_in, const int* in_sizes, int n_in,
                              void* d_out, int out_size, void* d_ws, size_t ws_size,
                              hipStream_t stream) {
  const float* x  = (const float*)d_in[0];
  const float* Wq = (const float*)d_in[1];
  const float* bq = (const float*)d_in[2];
  const float* Wk = (const float*)d_in[3];
  const float* bk = (const float*)d_in[4];
  const float* Wv = (const float*)d_in[5];
  const float* bv = (const float*)d_in[6];
  const float* Wo = (const float*)d_in[7];
  const float* bo = (const float*)d_in[8];
  const float* sg = (const float*)d_in[9];

  const int M = 8 * 64 * 64;          // 32768 tokens
  const size_t NE = (size_t)M * 1024; // 33,554,432 elements

  f16* xb  = (f16*)d_ws;              // x_f16; reused as attn buffer later
  f16* wqb = xb + NE;
  f16* wkb = wqb + 1024 * 1024;
  f16* wvb = wkb + 1024 * 1024;
  f16* wob = wvb + 1024 * 1024;
  f16* qb  = wob + 1024 * 1024;
  f16* kb  = qb + NE;
  f16* vb  = kb + NE;                 // total ws use: 276,824,064 bytes

  k_cvt_f16<<<2048, 256, 0, stream>>>(x, xb, (int)(NE / 8));
  k_cvt_f16<<<256, 256, 0, stream>>>(Wq, wqb, (1024 * 1024) / 8);
  k_cvt_f16<<<256, 256, 0, stream>>>(Wk, wkb, (1024 * 1024) / 8);
  k_cvt_f16<<<256, 256, 0, stream>>>(Wv, wvb, (1024 * 1024) / 8);
  k_cvt_f16<<<256, 256, 0, stream>>>(Wo, wob, (1024 * 1024) / 8);

  dim3 gg(1024 / 128, M / 128);       // bn fast => bn-blocks share A-tile in L2
  k_gemm_bt<false><<<gg, 256, 0, stream>>>(xb, wqb, bq, qb, M, 1024, 1024);
  k_gemm_bt<false><<<gg, 256, 0, stream>>>(xb, wkb, bk, kb, M, 1024, 1024);
  k_gemm_bt<false><<<gg, 256, 0, stream>>>(xb, wvb, bv, vb, M, 1024, 1024);

  f16* attn = xb;                     // x_f16 dead after the three GEMMs
  k_attn<false><<<512, 256, 0, stream>>>(qb, kb, vb, attn, sg);  // row: writes
  k_attn<true><<<512, 256, 0, stream>>>(qb, kb, vb, attn, sg);   // col: accumulates

  k_gemm_bt<true><<<gg, 256, 0, stream>>>(attn, wob, bo, (float*)d_out, M, 1024, 1024);
}

// Round 3
// 523.586 us; speedup vs baseline: 1.2391x; 1.2391x over previous
//
#include <hip/hip_runtime.h>

// GSA layer: q/k/v = x@Wqkv^T+b ; row+col attention with -gw*(i-j)^2 bias ; out = (r+c)@Wo^T+bo
// fp16 MFMA pipeline (fp32 accum, fp32 softmax).
// GEMM: 256x256 tile, BK=64, 8 waves, 8-phase schedule (T3+T4 counted vmcnt),
// LDS XOR swizzle (T2, both-sides involution per rule #21), setprio (T5),
// XCD-aware block swizzle (T1).

typedef _Float16 f16;
typedef __attribute__((ext_vector_type(8))) _Float16 f16x8;
typedef __attribute__((ext_vector_type(4))) float f32x4;

#define DEV __device__ __forceinline__

// ---------------- convert f32 -> f16 (vectorized, grid-stride) --------------
__global__ __launch_bounds__(256) void k_cvt_f16(const float* __restrict__ in,
                                                 f16* __restrict__ out, int n8) {
  int stride = gridDim.x * blockDim.x;
  for (int i = blockIdx.x * blockDim.x + threadIdx.x; i < n8; i += stride) {
    const float4* p = (const float4*)in + (size_t)i * 2;
    float4 a = p[0];
    float4 b = p[1];
    f16x8 o;
    o[0] = (f16)a.x; o[1] = (f16)a.y; o[2] = (f16)a.z; o[3] = (f16)a.w;
    o[4] = (f16)b.x; o[5] = (f16)b.y; o[6] = (f16)b.z; o[7] = (f16)b.w;
    *(f16x8*)(out + (size_t)i * 8) = o;
  }
}

// ---- C[M,N] = A[M,K]*B[N,K]^T + bias; 256^2 tile, BK=64, 8 waves, 8-phase ----
// Waves: wr=wid>>2 (2 M-halves), wc=wid&3 (4 N-quarters). Per-wave C: 128x64.
// LDS: smem[slot][mat][half][128*64] = 128 KiB. Half-buffer = 128 rows x 64 k.
// Swizzle: within a row (8 x 16B units), unit u holds global unit u^(row&7).
// Schedule per K-tile t (slot s=t&1), 4 phases:
//   P1: ds_read B(8)+Aq0(4); stage A0_{t+1}->s^1   (A_{t-1} freed end of prev K-tile)
//   P2: ds_read Aq1;         stage A1_{t+1}->s^1
//   P3: ds_read Aq2;         stage B0_{t+2}->s     (B_t freed after P1)
//   P4: ds_read Aq3;         stage B1_{t+2}->s ; vmcnt(4)  (only B_{t+2} may stay in flight)
// Each phase: [reads, stage, barrier, lgkmcnt(0), setprio(1), 16 MFMA, setprio(0), barrier]
template<bool C_F32>
__global__ __launch_bounds__(512, 2) void k_gemm256(const f16* __restrict__ A,
                                                    const f16* __restrict__ B,
                                                    const float* __restrict__ b0,
                                                    const float* __restrict__ b1,
                                                    const float* __restrict__ b2,
                                                    void* __restrict__ Cout,
                                                    int M, int N, int K) {
  __shared__ f16 smem[2][2][2][128 * 64];   // [slot][mat A=0/B=1][half][.] = 128 KiB

  const int tid = threadIdx.x;
  const int lane = tid & 63;
  const int wid = tid >> 6;
  const int wr = wid >> 2;        // 0..1  M-half
  const int wc = wid & 3;         // 0..3  N-quarter
  const int lane_r = lane & 15;
  const int g = lane >> 4;        // 0..3

  // T1: XCD-aware swizzle (nwg % 8 == 0 by construction)
  const int nwg = gridDim.x;
  const int bid = blockIdx.x;
  const int swz = (bid & 7) * (nwg >> 3) + (bid >> 3);
  const int nbn = N >> 8;
  const int bm = swz / nbn, bn = swz % nbn;

  // per-lane swizzled in-row element offsets for frag reads (16B unit = 8 f16)
  const int u0 = ((g) ^ (lane_r & 7)) * 8;        // khalf 0
  const int u1 = ((4 + g) ^ (lane_r & 7)) * 8;    // khalf 1
  // per-lane staging constants: lane covers LDS row l>>3, unit l&7 of its 1KB chunk;
  // inverse-swizzled global source unit = (l&7)^(l>>3)
  const int arow = lane >> 3;
  const int acol = ((lane & 7) ^ (lane >> 3)) * 8;

  const f16* Ag[2] = { A + (size_t)(bm * 256) * K, A + (size_t)(bm * 256 + 128) * K };
  const f16* Bg[2] = { B + (size_t)(bn * 256) * K, B + (size_t)(bn * 256 + 128) * K };

  f32x4 acc[8][4];
#pragma unroll
  for (int i = 0; i < 8; ++i)
#pragma unroll
    for (int j = 0; j < 4; ++j) acc[i][j] = (f32x4){0.f, 0.f, 0.f, 0.f};

  // cooperative stage of one 128x64 half-tile: 2 x global_load_lds per thread
#define STAGE(gbase, kt, lbase)                                                     \
  {                                                                                 \
    _Pragma("unroll") for (int i_ = 0; i_ < 2; ++i_) {                              \
      const f16* g_ = (gbase) + (size_t)(wid * 16 + i_ * 8 + arow) * K + (kt) * 64 + acol; \
      __builtin_amdgcn_global_load_lds(                                             \
          (const __attribute__((address_space(1))) void*)g_,                        \
          (__attribute__((address_space(3))) void*)((lbase) + (wid * 16 + i_ * 8) * 64), \
          16, 0, 0);                                                                \
    }                                                                               \
  }

#define MFMAQ(q)                                                                    \
  _Pragma("unroll") for (int mm = 0; mm < 2; ++mm)                                  \
  _Pragma("unroll") for (int n = 0; n < 4; ++n) {                                   \
    acc[(q)*2 + mm][n] = __builtin_amdgcn_mfma_f32_16x16x32_f16(afrag[mm][0], bfrag[n][0], acc[(q)*2 + mm][n], 0, 0, 0); \
    acc[(q)*2 + mm][n] = __builtin_amdgcn_mfma_f32_16x16x32_f16(afrag[mm][1], bfrag[n][1], acc[(q)*2 + mm][n], 0, 0, 0); \
  }

#define READ_A(q)                                                                   \
  _Pragma("unroll") for (int mm = 0; mm < 2; ++mm) {                                \
    const int rb_ = ((q)*32 + mm * 16 + lane_r) * 64;                               \
    afrag[mm][0] = *(const f16x8*)&As_[rb_ + u0];                                   \
    afrag[mm][1] = *(const f16x8*)&As_[rb_ + u1];                                   \
  }

  // mode: 2 = stage A&B + vmcnt(4); 1 = stage A only + vmcnt(0); 0 = none
#define KTILE(t, slot, mode)                                                        \
  {                                                                                 \
    f16* As_ = smem[slot][0][wr];                                                   \
    f16* Bs_ = smem[slot][1][wc >> 1];                                              \
    f16x8 bfrag[4][2], afrag[2][2];                                                 \
    _Pragma("unroll") for (int n = 0; n < 4; ++n) {                                 \
      const int rb_ = ((wc & 1) * 64 + n * 16 + lane_r) * 64;                       \
      bfrag[n][0] = *(const f16x8*)&Bs_[rb_ + u0];                                  \
      bfrag[n][1] = *(const f16x8*)&Bs_[rb_ + u1];                                  \
    }                                                                               \
    READ_A(0)                                                                       \
    if ((mode) >= 1) STAGE(Ag[0], (t) + 1, smem[(slot) ^ 1][0][0]);                 \
    asm volatile("s_waitcnt lgkmcnt(8)" ::: "memory");                              \
    __builtin_amdgcn_s_barrier();                                                   \
    asm volatile("s_waitcnt lgkmcnt(0)" ::: "memory");                              \
    __builtin_amdgcn_s_setprio(1);                                                  \
    MFMAQ(0)                                                                        \
    __builtin_amdgcn_s_setprio(0);                                                  \
    __builtin_amdgcn_s_barrier();                                                   \
    READ_A(1)                                                                       \
    if ((mode) >= 1) STAGE(Ag[1], (t) + 1, smem[(slot) ^ 1][0][1]);                 \
    __builtin_amdgcn_s_barrier();                                                   \
    asm volatile("s_waitcnt lgkmcnt(0)" ::: "memory");                              \
    __builtin_amdgcn_s_setprio(1);                                                  \
    MFMAQ(1)                                                                        \
    __builtin_amdgcn_s_setprio(0);                                                  \
    __builtin_amdgcn_s_barrier();                                                   \
    READ_A(2)                                                                       \
    if ((mode) == 2) STAGE(Bg[0], (t) + 2, smem[slot][1][0]);                       \
    __builtin_amdgcn_s_barrier();                                                   \
    asm volatile("s_waitcnt lgkmcnt(0)" ::: "memory");                              \
    __builtin_amdgcn_s_setprio(1);                                                  \
    MFMAQ(2)                                                                        \
    __builtin_amdgcn_s_setprio(0);                                                  \
    __builtin_amdgcn_s_barrier();                                                   \
    READ_A(3)                                                                       \
    if ((mode) == 2) STAGE(Bg[1], (t) + 2, smem[slot][1][1]);                       \
    if ((mode) == 2) { asm volatile("s_waitcnt vmcnt(4)" ::: "memory"); }           \
    else if ((mode) == 1) { asm volatile("s_waitcnt vmcnt(0)" ::: "memory"); }      \
    __builtin_amdgcn_s_barrier();                                                   \
    asm volatile("s_waitcnt lgkmcnt(0)" ::: "memory");                              \
    __builtin_amdgcn_s_setprio(1);                                                  \
    MFMAQ(3)                                                                        \
    __builtin_amdgcn_s_setprio(0);                                                  \
    __builtin_amdgcn_s_barrier();                                                   \
  }

  const int nt = K >> 6;   // K-tiles (>= 4, even)

  // prologue: K-tile 0 (A0,A1,B0,B1 -> slot0) + B of K-tile 1 -> slot1
  STAGE(Ag[0], 0, smem[0][0][0]);
  STAGE(Ag[1], 0, smem[0][0][1]);
  STAGE(Bg[0], 0, smem[0][1][0]);
  STAGE(Bg[1], 0, smem[0][1][1]);
  STAGE(Bg[0], 1, smem[1][1][0]);
  STAGE(Bg[1], 1, smem[1][1][1]);
  asm volatile("s_waitcnt vmcnt(4)" ::: "memory");   // K-tile 0 fully landed
  __builtin_amdgcn_s_barrier();

  for (int t = 0; t + 3 < nt; t += 2) {
    KTILE(t, 0, 2)
    KTILE(t + 1, 1, 2)
  }
  KTILE(nt - 2, 0, 1)
  KTILE(nt - 1, 1, 0)

  // epilogue: C row = bm*256 + wr*128 + mrep*16 + (lane>>4)*4 + r ; col = bn*256 + wc*64 + n*16 + (lane&15)
  const int mrow0 = bm * 256 + wr * 128 + (lane >> 4) * 4;
  const int ncol0 = bn * 256 + wc * 64 + (lane & 15);
#pragma unroll
  for (int n = 0; n < 4; ++n) {
    const int col = ncol0 + n * 16;
    const float* bp = (col < 1024) ? b0 : ((col < 2048) ? b1 : b2);
    const float bvv = bp[col & 1023];
#pragma unroll
    for (int mrep = 0; mrep < 8; ++mrep) {
#pragma unroll
      for (int r = 0; r < 4; ++r) {
        const int row = mrow0 + mrep * 16 + r;
        const float val = acc[mrep][n][r] + bvv;
        if (C_F32) ((float*)Cout)[(size_t)row * N + col] = val;
        else       ((f16*)Cout)[(size_t)row * N + col] = (f16)val;
      }
    }
  }
#undef KTILE
#undef READ_A
#undef MFMAQ
#undef STAGE
}

// ------------------- axis attention: one block per (b,line) -----------------
// qkv layout: [32768 tokens][3072] with q at +0, k at +1024, v at +2048.
// attn out: [32768][1024]. IS_COL=false: tokens blk*64+i. IS_COL=true:
// tokens (blk>>6)*4096 + i*64 + (blk&63); accumulates (RMW, race-free:
// one thread per element, kernels sequential on stream).
template<bool IS_COL>
__global__ __launch_bounds__(256) void k_attn(const f16* __restrict__ qkv,
                                              f16* __restrict__ attn,
                                              const float* __restrict__ sigma) {
  __shared__ union { float S[64][68]; f16 Vt[256][72]; } sm;  // S dead before Vt lives
  __shared__ f16 P[64][72];

  const int tid = threadIdx.x;
  const int lane = tid & 63;
  const int wid = tid >> 6;
  const int blk = blockIdx.x;

  size_t tok0; int tstr;
  if (IS_COL) { tok0 = (size_t)(blk >> 6) * 4096 + (blk & 63); tstr = 64; }
  else        { tok0 = (size_t)blk * 64;                       tstr = 1;  }
  const size_t ibase = tok0 * 3072;  const int  istr = tstr * 3072;
  const size_t obase = tok0 * 1024;  const int  ostr = tstr * 1024;

  const float sg = sigma[0];
  const float gw = 0.5f / (sg * sg);

  const int m0 = wid * 16;   // wave's query rows
  const int lr = lane & 15;
  const int lq = lane >> 4;

  // ---- phase A: S = Q K^T ----
  f32x4 sacc[4];
#pragma unroll
  for (int nt = 0; nt < 4; ++nt) sacc[nt] = (f32x4){0.f, 0.f, 0.f, 0.f};
  const f16* qp = qkv + ibase + (size_t)(m0 + lr) * istr + lq * 8;
  const f16* kp = qkv + ibase + 1024 + (size_t)lr * istr + lq * 8;
#pragma unroll 2
  for (int ks = 0; ks < 32; ++ks) {
    f16x8 af = *(const f16x8*)(qp + ks * 32);
#pragma unroll
    for (int nt = 0; nt < 4; ++nt) {
      f16x8 bfr = *(const f16x8*)(kp + (size_t)nt * 16 * istr + ks * 32);
      sacc[nt] = __builtin_amdgcn_mfma_f32_16x16x32_f16(af, bfr, sacc[nt], 0, 0, 0);
    }
  }
#pragma unroll
  for (int nt = 0; nt < 4; ++nt)
#pragma unroll
    for (int r = 0; r < 4; ++r) {
      const int row = m0 + lq * 4 + r;
      const int col = nt * 16 + lr;
      const float dd = (float)(row - col);
      sm.S[row][col] = sacc[nt][r] - gw * dd * dd;
    }
  __syncthreads();

  // ---- phase B: row softmax, 4 threads per row ----
  {
    const int r = tid >> 2, s4 = tid & 3;
    const float4* sp = (const float4*)&sm.S[r][s4 * 16];
    float vals[16];
#pragma unroll
    for (int j = 0; j < 4; ++j) {
      float4 t = sp[j];
      vals[j * 4 + 0] = t.x; vals[j * 4 + 1] = t.y; vals[j * 4 + 2] = t.z; vals[j * 4 + 3] = t.w;
    }
    float mx = vals[0];
#pragma unroll
    for (int j = 1; j < 16; ++j) mx = fmaxf(mx, vals[j]);
    mx = fmaxf(mx, __shfl_xor(mx, 1));
    mx = fmaxf(mx, __shfl_xor(mx, 2));
    float sum = 0.f;
#pragma unroll
    for (int j = 0; j < 16; ++j) { vals[j] = __expf(vals[j] - mx); sum += vals[j]; }
    sum += __shfl_xor(sum, 1);
    sum += __shfl_xor(sum, 2);
    const float inv = 1.f / sum;
#pragma unroll
    for (int j = 0; j < 16; ++j) P[r][s4 * 16 + j] = (f16)(vals[j] * inv);
  }
  __syncthreads();

  // ---- phase C: O = P V ; V transposed through LDS in 256-col chunks ----
  const f16x8 af0 = *(const f16x8*)&P[m0 + lr][lq * 8];
  const f16x8 af1 = *(const f16x8*)&P[m0 + lr][32 + lq * 8];

  const int kr = tid & 63;
  const int cg = tid >> 6;
  const f16* vp = qkv + ibase + 2048 + (size_t)kr * istr;

  for (int c = 0; c < 4; ++c) {
#pragma unroll
    for (int j8 = 0; j8 < 8; ++j8) {
      const int cl = cg * 64 + j8 * 8;
      f16x8 vv = *(const f16x8*)(vp + c * 256 + cl);
#pragma unroll
      for (int e = 0; e < 8; ++e) sm.Vt[cl + e][kr] = vv[e];
    }
    __syncthreads();
#pragma unroll
    for (int nt = 0; nt < 16; ++nt) {
      const f16x8 bf0 = *(const f16x8*)&sm.Vt[nt * 16 + lr][lq * 8];
      const f16x8 bf1 = *(const f16x8*)&sm.Vt[nt * 16 + lr][32 + lq * 8];
      f32x4 o = (f32x4){0.f, 0.f, 0.f, 0.f};
      o = __builtin_amdgcn_mfma_f32_16x16x32_f16(af0, bf0, o, 0, 0, 0);
      o = __builtin_amdgcn_mfma_f32_16x16x32_f16(af1, bf1, o, 0, 0, 0);
#pragma unroll
      for (int r = 0; r < 4; ++r) {
        const int row = m0 + lq * 4 + r;
        const int col = c * 256 + nt * 16 + lr;
        const size_t addr = obase + (size_t)row * ostr + col;
        float val = o[r];
        if (IS_COL) val += (float)attn[addr];
        attn[addr] = (f16)val;
      }
    }
    __syncthreads();
  }
}

extern "C" void kernel_launch(void* const* d_in, const int* in_sizes, int n_in,
                              void* d_out, int out_size, void* d_ws, size_t ws_size,
                              hipStream_t stream) {
  const float* x  = (const float*)d_in[0];
  const float* Wq = (const float*)d_in[1];
  const float* bq = (const float*)d_in[2];
  const float* Wk = (const float*)d_in[3];
  const float* bk = (const float*)d_in[4];
  const float* Wv = (const float*)d_in[5];
  const float* bv = (const float*)d_in[6];
  const float* Wo = (const float*)d_in[7];
  const float* bo = (const float*)d_in[8];
  const float* sg = (const float*)d_in[9];

  const int M = 8 * 64 * 64;          // 32768 tokens
  const size_t NE = (size_t)M * 1024;

  f16* xb   = (f16*)d_ws;             // 33.5M ; reused as attn buffer
  f16* wqkv = xb + NE;                // 3072 x 1024
  f16* wob  = wqkv + 3 * 1024 * 1024; // 1024 x 1024
  f16* qkv  = wob + 1024 * 1024;      // 32768 x 3072  (total = 276,824,064 B)

  k_cvt_f16<<<2048, 256, 0, stream>>>(x, xb, (int)(NE / 8));
  k_cvt_f16<<<256, 256, 0, stream>>>(Wq, wqkv,                   (1024 * 1024) / 8);
  k_cvt_f16<<<256, 256, 0, stream>>>(Wk, wqkv + 1024 * 1024,     (1024 * 1024) / 8);
  k_cvt_f16<<<256, 256, 0, stream>>>(Wv, wqkv + 2 * 1024 * 1024, (1024 * 1024) / 8);
  k_cvt_f16<<<256, 256, 0, stream>>>(Wo, wob,                    (1024 * 1024) / 8);

  // fused QKV GEMM: [32768,1024] x [3072,1024]^T -> [32768,3072]
  k_gemm256<false><<<(M / 256) * (3072 / 256), 512, 0, stream>>>(
      xb, wqkv, bq, bk, bv, qkv, M, 3072, 1024);

  f16* attn = xb;                     // x_f16 dead after QKV GEMM
  k_attn<false><<<512, 256, 0, stream>>>(qkv, attn, sg);  // row: writes
  k_attn<true><<<512, 256, 0, stream>>>(qkv, attn, sg);   // col: accumulates

  // output GEMM: [32768,1024] x [1024,1024]^T -> f32 out
  k_gemm256<true><<<(M / 256) * (1024 / 256), 512, 0, stream>>>(
      attn, wob, bo, bo, bo, (float*)d_out, M, 1024, 1024);
}